// Round 5
// baseline (915.828 us; speedup 1.0000x reference)
//
#include <hip/hip_runtime.h>
#include <hip/hip_bf16.h>

// out[1,512] = sum_rows(relu(concat(v0,v1) @ W.T + b))
// Barrier-free, LDS-free main loop. Block = 32-row x 512-col panel, 8 waves.
// A: global->reg f32, depth-2, cvt->bf16 (read ONCE from HBM, L1-shared in block).
// B: Wb (bf16, L2-resident) -> reg direct, depth-2. Compiler emits counted vmcnt.
// Deterministic 2-stage reduction via d_ws partials.

typedef __bf16 bf16x8 __attribute__((ext_vector_type(8)));
typedef float  f32x4  __attribute__((ext_vector_type(4)));
typedef unsigned short u16x4 __attribute__((ext_vector_type(4)));

#define NK 16        // 512 / 32
#define PROWS 32     // rows per panel (N % 32 == 0 for N=200000)

static __device__ __forceinline__ unsigned short f2bf(float f) {
    return __builtin_bit_cast(unsigned short, (__bf16)f);
}
static __device__ __forceinline__ bf16x8 pack8(float4 a, float4 b) {
    bf16x8 o;
    o[0] = (__bf16)a.x; o[1] = (__bf16)a.y; o[2] = (__bf16)a.z; o[3] = (__bf16)a.w;
    o[4] = (__bf16)b.x; o[5] = (__bf16)b.y; o[6] = (__bf16)b.z; o[7] = (__bf16)b.w;
    return o;
}

__global__ void conv_w_bf16(const float* __restrict__ W, unsigned short* __restrict__ Wb) {
    int idx = (blockIdx.x * blockDim.x + threadIdx.x) * 4;   // 512*512 elems, exact
    float4 f = *(const float4*)(W + idx);
    u16x4 p;
    p[0] = f2bf(f.x); p[1] = f2bf(f.y); p[2] = f2bf(f.z); p[3] = f2bf(f.w);
    *(u16x4*)(Wb + idx) = p;
}

template<bool WBF16>
__global__ __launch_bounds__(512) void fused_gemm_pool(
    const float* __restrict__ v0, const float* __restrict__ v1,
    const float* __restrict__ Wf, const unsigned short* __restrict__ Wb,
    const float* __restrict__ b,
    float* __restrict__ partial, int N, int numPanels, int G)
{
    int bid = blockIdx.x;
    int tid = threadIdx.x, wid = tid >> 6, lane = tid & 63;
    int l15 = lane & 15, l4 = lane >> 4;

    // B fragment element offsets: col = wid*64 + nf*16 + l15, k-chunk = l4*8
    int offB[4];
    #pragma unroll
    for (int nf = 0; nf < 4; ++nf)
        offB[nf] = (wid * 64 + nf * 16 + l15) * 512 + l4 * 8;

    float bv[4];
    #pragma unroll
    for (int nf = 0; nf < 4; ++nf) bv[nf] = b[wid * 64 + nf * 16 + l15];

    float csum[4] = {0.f, 0.f, 0.f, 0.f};

    float4 Abuf[2][2][2];   // [dbuf][mf][half] f32 staging
    bf16x8 Bbuf[2][4];      // [dbuf][nf]
    f32x4  acc[2][4];
    #pragma unroll
    for (int mf = 0; mf < 2; ++mf)
        #pragma unroll
        for (int nf = 0; nf < 4; ++nf) acc[mf][nf] = (f32x4){0.f, 0.f, 0.f, 0.f};

    int offA0 = 0, offA1 = 0;
    int prevRowBase = -1;

    auto loadA = [&](int kt, int d) {
        const float* src = (kt < 8) ? v0 : v1;
        int k0 = (kt & 7) * 32;
        Abuf[d][0][0] = *(const float4*)(src + offA0 + k0);
        Abuf[d][0][1] = *(const float4*)(src + offA0 + k0 + 4);
        Abuf[d][1][0] = *(const float4*)(src + offA1 + k0);
        Abuf[d][1][1] = *(const float4*)(src + offA1 + k0 + 4);
    };
    auto loadB = [&](int kt, int d) {
        if constexpr (WBF16) {
            #pragma unroll
            for (int nf = 0; nf < 4; ++nf)
                Bbuf[d][nf] = *(const bf16x8*)(Wb + offB[nf] + kt * 32);
        } else {
            #pragma unroll
            for (int nf = 0; nf < 4; ++nf) {
                const float* pw = Wf + offB[nf] + kt * 32;
                Bbuf[d][nf] = pack8(*(const float4*)pw, *(const float4*)(pw + 4));
            }
        }
    };
    auto epilogue = [&](int rowBase) {
        #pragma unroll
        for (int nf = 0; nf < 4; ++nf) {
            float bb = bv[nf];
            #pragma unroll
            for (int mf = 0; mf < 2; ++mf) {
                int rbase = rowBase + mf * 16 + l4 * 4;
                #pragma unroll
                for (int j = 0; j < 4; ++j) {
                    float v = fmaxf(acc[mf][nf][j] + bb, 0.f);
                    if (rbase + j < N) csum[nf] += v;
                }
            }
        }
    };

    for (int p = bid; p < numPanels; p += G) {
        int rowBase = p * PROWS;
        // clamped row offsets (clamp only active on a ragged tail)
        offA0 = min(rowBase + l15,      N - 1) * 256 + l4 * 8;
        offA1 = min(rowBase + 16 + l15, N - 1) * 256 + l4 * 8;

        loadA(0, 0); loadB(0, 0);                 // issue panel's first loads

        if (prevRowBase >= 0) epilogue(prevRowBase);  // covers refill latency
        #pragma unroll
        for (int mf = 0; mf < 2; ++mf)
            #pragma unroll
            for (int nf = 0; nf < 4; ++nf) acc[mf][nf] = (f32x4){0.f, 0.f, 0.f, 0.f};

        #pragma unroll
        for (int kt = 0; kt < NK; ++kt) {
            int cur = kt & 1;
            if (kt + 1 < NK) { loadA(kt + 1, cur ^ 1); loadB(kt + 1, cur ^ 1); }
            bf16x8 af0 = pack8(Abuf[cur][0][0], Abuf[cur][0][1]);
            bf16x8 af1 = pack8(Abuf[cur][1][0], Abuf[cur][1][1]);
            #pragma unroll
            for (int nf = 0; nf < 4; ++nf) {
                acc[0][nf] = __builtin_amdgcn_mfma_f32_16x16x32_bf16(af0, Bbuf[cur][nf], acc[0][nf], 0, 0, 0);
                acc[1][nf] = __builtin_amdgcn_mfma_f32_16x16x32_bf16(af1, Bbuf[cur][nf], acc[1][nf], 0, 0, 0);
            }
        }
        prevRowBase = rowBase;
    }
    if (prevRowBase >= 0) epilogue(prevRowBase);

    // cross-lane column reduce: lanes l, l^16, l^32, l^48 share a column
    #pragma unroll
    for (int nf = 0; nf < 4; ++nf) {
        float s = csum[nf];
        s += __shfl_xor(s, 16);
        s += __shfl_xor(s, 32);
        if (lane < 16)
            partial[(size_t)bid * 512 + wid * 64 + nf * 16 + lane] = s;
    }
}

__global__ void reduce_partials(const float* __restrict__ partial,
                                float* __restrict__ out, int G)
{
    int c = threadIdx.x;
    if (c < 512) {
        float s = 0.f;
        for (int g = 0; g < G; ++g) s += partial[(size_t)g * 512 + c];
        out[c] = s;
    }
}

extern "C" void kernel_launch(void* const* d_in, const int* in_sizes, int n_in,
                              void* d_out, int out_size, void* d_ws, size_t ws_size,
                              hipStream_t stream)
{
    const float* v0 = (const float*)d_in[0];
    const float* v1 = (const float*)d_in[1];
    const float* Wf = (const float*)d_in[2];
    const float* b  = (const float*)d_in[3];
    float* out      = (float*)d_out;

    int N = in_sizes[0] / 256;
    int numPanels = (N + PROWS - 1) / PROWS;

    const size_t wbytes = (size_t)512 * 512 * sizeof(unsigned short);   // 512 KB
    auto pbytes = [](int G) { return (size_t)G * 512 * sizeof(float); };

    int G; bool useWb;
    if      (ws_size >= wbytes + pbytes(1024)) { G = 1024; useWb = true;  }
    else if (ws_size >= wbytes + pbytes(512))  { G = 512;  useWb = true;  }
    else if (ws_size >= pbytes(512))           { G = 512;  useWb = false; }
    else if (ws_size >= pbytes(256))           { G = 256;  useWb = false; }
    else                                       { G = 128;  useWb = false; }

    if (useWb) {
        unsigned short* Wb = (unsigned short*)d_ws;
        float* partial = (float*)((char*)d_ws + wbytes);
        conv_w_bf16<<<dim3(256), dim3(256), 0, stream>>>(Wf, Wb);
        fused_gemm_pool<true><<<dim3(G), dim3(512), 0, stream>>>(
            v0, v1, Wf, Wb, b, partial, N, numPanels, G);
        reduce_partials<<<dim3(1), dim3(512), 0, stream>>>(partial, out, G);
    } else {
        float* partial = (float*)d_ws;
        fused_gemm_pool<false><<<dim3(G), dim3(512), 0, stream>>>(
            v0, v1, Wf, nullptr, b, partial, N, numPanels, G);
        reduce_partials<<<dim3(1), dim3(512), 0, stream>>>(partial, out, G);
    }
}

// Round 6
// 459.742 us; speedup vs baseline: 1.9920x; 1.9920x over previous
//
#include <hip/hip_runtime.h>
#include <hip/hip_bf16.h>

// out[1,512] = sum_rows(relu(concat(v0,v1) @ W.T + b))
// R2 structure, occupancy-fixed: BM 128->64 (wave tile 32x64, acc 32 AGPR),
// ~4 waves/SIMD, grid 2048 = 4 blocks/CU resident. W pre-converted to bf16;
// B staged via global_load_lds (pre-swizzled source); A reg-staged depth-2.

typedef __bf16 bf16x8 __attribute__((ext_vector_type(8)));
typedef float  f32x4  __attribute__((ext_vector_type(4)));
typedef unsigned short u16x4 __attribute__((ext_vector_type(4)));

#define BM 64
#define BN 128
#define BK 32
#define NK 16          // 512 / 32

static __device__ __forceinline__ int swz(int r) { return (r & 3) ^ ((r >> 2) & 3); }
static __device__ __forceinline__ unsigned short f2bf(float f) {
    return __builtin_bit_cast(unsigned short, (__bf16)f);
}
static __device__ __forceinline__ bf16x8 pack8(float4 a, float4 b) {
    bf16x8 o;
    o[0] = (__bf16)a.x; o[1] = (__bf16)a.y; o[2] = (__bf16)a.z; o[3] = (__bf16)a.w;
    o[4] = (__bf16)b.x; o[5] = (__bf16)b.y; o[6] = (__bf16)b.z; o[7] = (__bf16)b.w;
    return o;
}

#define GLDS16(G, L) __builtin_amdgcn_global_load_lds(                       \
    (const __attribute__((address_space(1))) void*)(G),                     \
    (__attribute__((address_space(3))) void*)(L), 16, 0, 0)

__global__ void conv_w_bf16(const float* __restrict__ W, unsigned short* __restrict__ Wb) {
    int idx = (blockIdx.x * blockDim.x + threadIdx.x) * 4;   // 512*512 elems, exact
    float4 f = *(const float4*)(W + idx);
    u16x4 p;
    p[0] = f2bf(f.x); p[1] = f2bf(f.y); p[2] = f2bf(f.z); p[3] = f2bf(f.w);
    *(u16x4*)(Wb + idx) = p;
}

template<bool WBF16>
__global__ __launch_bounds__(256) void fused_gemm_pool(
    const float* __restrict__ v0, const float* __restrict__ v1,
    const float* __restrict__ Wf, const unsigned short* __restrict__ Wb,
    const float* __restrict__ b,
    float* __restrict__ partial, int N, int numRB, int slots)
{
    __shared__ unsigned short As[2][BM * BK];   // 2 x 4 KB
    __shared__ unsigned short Bs[2][BN * BK];   // 2 x 8 KB
    __shared__ float ldsPart[2][128];

    int bid   = blockIdx.x;
    int group = bid >> 5;          // 32 blocks per group = 8 XCDs x 4 col-blocks
    int xcd   = bid & 7;
    int cb    = (bid >> 3) & 3;    // col-block: siblings share XCD -> A L2 reuse
    int slot  = group * 8 + xcd;   // 0..slots-1

    int tid = threadIdx.x, wid = tid >> 6, lane = tid & 63;
    int wr = wid >> 1, wc = wid & 1, l15 = lane & 15, l4 = lane >> 4;

    // ---- per-thread constant offsets ----
    int rowA = tid >> 2, colA = tid & 3;               // A: 256 chunks of 8 f32
    int offAg = rowA * 256 + colA * 8;                 // f32 elements (+k0)
    int offAw = rowA * BK + ((colA ^ swz(rowA)) * 8);  // ushort offset in As

    int offBgl[2], offBg[2], offBw[2];
    #pragma unroll
    for (int j = 0; j < 2; ++j) {
        int mu = (wid + j * 4) * 64 + lane;            // 512 chunks of 8 bf16
        int br = mu >> 2, bc = mu & 3;
        offBgl[j] = (cb * 128 + br) * 512 + ((bc ^ swz(br)) * 8);  // bf16 src (+kt*32)
        offBg[j]  = (cb * 128 + br) * 512 + bc * 8;                // f32 fallback
        offBw[j]  = br * BK + ((bc ^ swz(br)) * 8);
    }
    int offAf[2], offBf[4];
    #pragma unroll
    for (int f = 0; f < 2; ++f) {
        int r = wr * 32 + f * 16 + l15;
        offAf[f] = r * BK + ((l4 ^ swz(r)) * 8);
    }
    #pragma unroll
    for (int f = 0; f < 4; ++f) {
        int cc = wc * 64 + f * 16 + l15;
        offBf[f] = cc * BK + ((l4 ^ swz(cc)) * 8);
    }

    float bv[4];
    #pragma unroll
    for (int nf = 0; nf < 4; ++nf) bv[nf] = b[cb * 128 + wc * 64 + nf * 16 + l15];

    float csum[4] = {0.f, 0.f, 0.f, 0.f};
    float4 rA[2][2];       // depth-2 A staging (one 8-float chunk per thread)
    float4 rB[2][4];       // f32-W fallback staging

    for (int rbk = slot; rbk < numRB; rbk += slots) {
        int rowBase = rbk * BM;

        f32x4 acc[2][4];
        #pragma unroll
        for (int mf = 0; mf < 2; ++mf)
            #pragma unroll
            for (int nf = 0; nf < 4; ++nf)
                acc[mf][nf] = (f32x4){0.f, 0.f, 0.f, 0.f};

        auto loadA = [&](int kt, int s) {
            const float* src = (kt < 8) ? v0 : v1;
            int k0 = (kt & 7) * 32;
            float4 f0 = {0,0,0,0}, f1 = {0,0,0,0};
            if (rowBase + rowA < N) {
                const float* p = src + (size_t)rowBase * 256 + offAg + k0;
                f0 = *(const float4*)p;
                f1 = *(const float4*)(p + 4);
            }
            rA[s][0] = f0; rA[s][1] = f1;
        };
        auto writeA = [&](int s, int buf) {
            *(bf16x8*)&As[buf][offAw] = pack8(rA[s][0], rA[s][1]);
        };
        auto stageBglds = [&](int kt, int buf) {
            int k0 = kt * 32;
            #pragma unroll
            for (int j = 0; j < 2; ++j)
                GLDS16(Wb + offBgl[j] + k0, &Bs[buf][(wid + j * 4) * 512]);
        };
        auto loadB = [&](int kt, int s) {   // fallback: W f32
            int k0 = kt * 32;
            #pragma unroll
            for (int j = 0; j < 2; ++j) {
                const float* p = Wf + offBg[j] + k0;
                rB[s][j * 2]     = *(const float4*)p;
                rB[s][j * 2 + 1] = *(const float4*)(p + 4);
            }
        };
        auto writeB = [&](int s, int buf) {
            #pragma unroll
            for (int j = 0; j < 2; ++j)
                *(bf16x8*)&Bs[buf][offBw[j]] = pack8(rB[s][j * 2], rB[s][j * 2 + 1]);
        };

        // ---- prologue ----
        if constexpr (WBF16) stageBglds(0, 0); else loadB(0, 0);
        loadA(0, 0);
        loadA(1, 1);
        if constexpr (!WBF16) loadB(1, 1);
        writeA(0, 0);
        if constexpr (!WBF16) writeB(0, 0);

        // ---- K loop: 1 barrier/step; next-next loads issued right after it ----
        #pragma unroll
        for (int kt = 0; kt < NK; ++kt) {
            int cur = kt & 1;
            __syncthreads();                 // As/Bs[cur] staged & visible
            if constexpr (WBF16) {
                if (kt + 1 < NK) stageBglds(kt + 1, cur ^ 1);
            }
            if (kt + 2 < NK) {
                loadA(kt + 2, cur);          // full body of flight before next drain
                if constexpr (!WBF16) loadB(kt + 2, cur);
            }
            bf16x8 af[2], bf[4];
            #pragma unroll
            for (int f = 0; f < 2; ++f) af[f] = *(const bf16x8*)&As[cur][offAf[f]];
            #pragma unroll
            for (int f = 0; f < 4; ++f) bf[f] = *(const bf16x8*)&Bs[cur][offBf[f]];
            #pragma unroll
            for (int mf = 0; mf < 2; ++mf)
                #pragma unroll
                for (int nf = 0; nf < 4; ++nf)
                    acc[mf][nf] = __builtin_amdgcn_mfma_f32_16x16x32_bf16(
                        af[mf], bf[nf], acc[mf][nf], 0, 0, 0);
            if (kt + 1 < NK) {
                writeA(cur ^ 1, cur ^ 1);    // counted vmcnt on kt+1 A loads
                if constexpr (!WBF16) writeB(cur ^ 1, cur ^ 1);
            }
        }

        // ---- epilogue: bias + relu + row-mask -> per-lane column partials ----
        #pragma unroll
        for (int nf = 0; nf < 4; ++nf) {
            float bb = bv[nf];
            #pragma unroll
            for (int mf = 0; mf < 2; ++mf) {
                int rbase = rowBase + wr * 32 + mf * 16 + l4 * 4;
                #pragma unroll
                for (int r = 0; r < 4; ++r) {
                    float v = fmaxf(acc[mf][nf][r] + bb, 0.f);
                    if (rbase + r < N) csum[nf] += v;
                }
            }
        }
    }

    // ---- cross-lane column reduce: lanes l, l^16, l^32, l^48 share a column ----
    #pragma unroll
    for (int nf = 0; nf < 4; ++nf) {
        float s = csum[nf];
        s += __shfl_xor(s, 16);
        s += __shfl_xor(s, 32);
        if (lane < 16) ldsPart[wr][wc * 64 + nf * 16 + lane] = s;
    }
    __syncthreads();
    if (tid < 128)
        partial[(size_t)slot * 512 + cb * 128 + tid] = ldsPart[0][tid] + ldsPart[1][tid];
}

__global__ void reduce_partials(const float* __restrict__ partial,
                                float* __restrict__ out, int slots)
{
    int c = threadIdx.x;
    if (c < 512) {
        float s = 0.f;
        for (int i = 0; i < slots; ++i) s += partial[(size_t)i * 512 + c];
        out[c] = s;
    }
}

extern "C" void kernel_launch(void* const* d_in, const int* in_sizes, int n_in,
                              void* d_out, int out_size, void* d_ws, size_t ws_size,
                              hipStream_t stream)
{
    const float* v0 = (const float*)d_in[0];
    const float* v1 = (const float*)d_in[1];
    const float* Wf = (const float*)d_in[2];
    const float* b  = (const float*)d_in[3];
    float* out      = (float*)d_out;

    int N = in_sizes[0] / 256;
    int numRB = (N + BM - 1) / BM;

    const size_t wbytes = (size_t)512 * 512 * sizeof(unsigned short);   // 512 KB
    auto pbytes = [](int s) { return (size_t)s * 512 * sizeof(float); };

    int slots; bool useWb;
    if      (ws_size >= wbytes + pbytes(512)) { slots = 512; useWb = true;  }
    else if (ws_size >= wbytes + pbytes(256)) { slots = 256; useWb = true;  }
    else if (ws_size >= pbytes(512))          { slots = 512; useWb = false; }
    else if (ws_size >= pbytes(256))          { slots = 256; useWb = false; }
    else                                      { slots = 128; useWb = false; }

    if (useWb) {
        unsigned short* Wb = (unsigned short*)d_ws;
        float* partial = (float*)((char*)d_ws + wbytes);
        conv_w_bf16<<<dim3(256), dim3(256), 0, stream>>>(Wf, Wb);
        fused_gemm_pool<true><<<dim3(slots * 4), dim3(256), 0, stream>>>(
            v0, v1, Wf, Wb, b, partial, N, numRB, slots);
        reduce_partials<<<dim3(1), dim3(512), 0, stream>>>(partial, out, slots);
    } else {
        float* partial = (float*)d_ws;
        fused_gemm_pool<false><<<dim3(slots * 4), dim3(256), 0, stream>>>(
            v0, v1, Wf, nullptr, b, partial, N, numRB, slots);
        reduce_partials<<<dim3(1), dim3(512), 0, stream>>>(partial, out, slots);
    }
}

// Round 7
// 377.644 us; speedup vs baseline: 2.4251x; 1.2174x over previous
//
#include <hip/hip_runtime.h>
#include <hip/hip_bf16.h>

// out[1,512] = sum_rows(relu(concat(v0,v1) @ W.T + b))
// Counted-vmcnt schedule (T3/T4): raw s_barrier + s_waitcnt vmcnt(4) per K-step
// keeps A loads in flight across the barrier. A: global->reg (per-wave rows,
// 64B-coalesced, depth-2). B: Wb bf16 via global_load_lds (pre-swizzled src),
// double-buffered 8KB LDS. Deterministic 2-stage reduction.

typedef __bf16 bf16x8 __attribute__((ext_vector_type(8)));
typedef float  f32x4  __attribute__((ext_vector_type(4)));
typedef unsigned short u16x4 __attribute__((ext_vector_type(4)));

#define BM 128         // 4 waves x 32 rows
#define BN 128
#define BK 32
#define NK 16          // 512 / 32
#define NCB 4

static __device__ __forceinline__ int swz(int r) { return (r & 3) ^ ((r >> 2) & 3); }
static __device__ __forceinline__ unsigned short f2bf(float f) {
    return __builtin_bit_cast(unsigned short, (__bf16)f);
}
static __device__ __forceinline__ bf16x8 pack8(float4 a, float4 b) {
    bf16x8 o;
    o[0] = (__bf16)a.x; o[1] = (__bf16)a.y; o[2] = (__bf16)a.z; o[3] = (__bf16)a.w;
    o[4] = (__bf16)b.x; o[5] = (__bf16)b.y; o[6] = (__bf16)b.z; o[7] = (__bf16)b.w;
    return o;
}

#define GLDS16(G, L) __builtin_amdgcn_global_load_lds(                       \
    (const __attribute__((address_space(1))) void*)(G),                     \
    (__attribute__((address_space(3))) void*)(L), 16, 0, 0)

__global__ void conv_w_bf16(const float* __restrict__ W, unsigned short* __restrict__ Wb) {
    int idx = (blockIdx.x * blockDim.x + threadIdx.x) * 4;   // 512*512 elems, exact
    float4 f = *(const float4*)(W + idx);
    u16x4 p;
    p[0] = f2bf(f.x); p[1] = f2bf(f.y); p[2] = f2bf(f.z); p[3] = f2bf(f.w);
    *(u16x4*)(Wb + idx) = p;
}

template<bool WBF16>
__global__ __launch_bounds__(256) void fused_gemm_pool(
    const float* __restrict__ v0, const float* __restrict__ v1,
    const unsigned short* __restrict__ Wb, const float* __restrict__ Wf,
    const float* __restrict__ b,
    float* __restrict__ partial, int N, int numRB, int slots)
{
    __shared__ unsigned short Bs[2][BN * BK];   // 2 x 8 KB, swizzled chunks
    __shared__ float ldsPart[4][128];

    int bid   = blockIdx.x;
    int group = bid >> 5;          // 32 blocks/group = 8 XCDs x 4 col-blocks
    int xcd   = bid & 7;
    int cb    = (bid >> 3) & 3;    // col-block siblings share XCD -> A L2 reuse
    int slot  = group * 8 + xcd;

    int tid = threadIdx.x, wid = tid >> 6, lane = tid & 63;
    int l15 = lane & 15, l4 = lane >> 4;

    // ---- B staging/read offsets (constant) ----
    int offBgl[2];
    #pragma unroll
    for (int j = 0; j < 2; ++j) {
        int mu = (wid + j * 4) * 64 + lane;            // 512 chunks of 8 bf16
        int br = mu >> 2, bc = mu & 3;
        offBgl[j] = (cb * 128 + br) * 512 + ((bc ^ swz(br)) * 8);  // +kt*32
    }
    int offBf[8];
    #pragma unroll
    for (int nf = 0; nf < 8; ++nf) {
        int cc = nf * 16 + l15;
        offBf[nf] = cc * BK + ((l4 ^ swz(cc)) * 8);
    }

    float bv[8];
    #pragma unroll
    for (int nf = 0; nf < 8; ++nf) bv[nf] = b[cb * 128 + nf * 16 + l15];

    float csum[8] = {0.f, 0.f, 0.f, 0.f, 0.f, 0.f, 0.f, 0.f};

    float4 As_[2][2][2];   // [slot][mf][half], f32 staging (depth 2)
    size_t offA[2];        // per-mf element offset (clamped row)

    auto computeOffA = [&](int rbk) {
        #pragma unroll
        for (int mf = 0; mf < 2; ++mf) {
            int row = rbk * BM + wid * 32 + mf * 16 + l15;
            offA[mf] = (size_t)min(row, N - 1) * 256 + l4 * 8;
        }
    };
    auto loadA = [&](int kt, int s) {   // 4 dwordx4, fully coalesced
        const float* src = (kt < 8) ? v0 : v1;
        int k0 = (kt & 7) * 32;
        #pragma unroll
        for (int mf = 0; mf < 2; ++mf) {
            const float* p = src + offA[mf] + k0;
            As_[s][mf][0] = *(const float4*)p;
            As_[s][mf][1] = *(const float4*)(p + 4);
        }
    };
    auto stageB = [&](int kt, int buf) {
        int k0 = kt * 32;
        #pragma unroll
        for (int j = 0; j < 2; ++j)
            GLDS16(Wb + offBgl[j] + k0, &Bs[buf][(wid + j * 4) * 512]);
    };

    int rbk = slot;
    if (rbk < numRB) {
        computeOffA(rbk);
        if constexpr (WBF16) {
            stageB(0, 0);
            __builtin_amdgcn_sched_barrier(0);
        }
        loadA(0, 0);
    }

    for (; rbk < numRB; rbk += slots) {
        f32x4 acc[2][8];
        #pragma unroll
        for (int mf = 0; mf < 2; ++mf)
            #pragma unroll
            for (int nf = 0; nf < 8; ++nf)
                acc[mf][nf] = (f32x4){0.f, 0.f, 0.f, 0.f};

        #pragma unroll
        for (int kt = 0; kt < NK; ++kt) {
            const int cur = kt & 1;
            if constexpr (WBF16) {
                // drain only this wave's 2 B-DMAs (A loads stay in flight),
                // then barrier: all waves' B DMA complete + buffers swapped.
                asm volatile("s_waitcnt vmcnt(4)" ::: "memory");
                __builtin_amdgcn_s_barrier();
            }
            if (kt + 1 < NK) {
                if constexpr (WBF16) {
                    stageB(kt + 1, cur ^ 1);
                    __builtin_amdgcn_sched_barrier(0);   // pin B-before-A issue order
                }
                loadA(kt + 1, cur ^ 1);
            } else {
                int nr = rbk + slots;
                if (nr < numRB) {
                    computeOffA(nr);
                    if constexpr (WBF16) {
                        stageB(0, 0);
                        __builtin_amdgcn_sched_barrier(0);
                    }
                    loadA(0, 0);
                }
            }
            // A fragments (auto counted-vmcnt wait)
            bf16x8 af[2];
            #pragma unroll
            for (int mf = 0; mf < 2; ++mf)
                af[mf] = pack8(As_[cur][mf][0], As_[cur][mf][1]);
            // B fragments in two halves (lower register pressure)
            #pragma unroll
            for (int h = 0; h < 2; ++h) {
                bf16x8 bf[4];
                #pragma unroll
                for (int i = 0; i < 4; ++i) {
                    if constexpr (WBF16) {
                        bf[i] = *(const bf16x8*)&Bs[cur][offBf[h * 4 + i]];
                    } else {
                        int cc = cb * 128 + (h * 4 + i) * 16 + l15;
                        const float* pw = Wf + (size_t)cc * 512 + (kt & 7) * 32 + (kt >> 3) * 256 + l4 * 8;
                        bf[i] = pack8(*(const float4*)pw, *(const float4*)(pw + 4));
                    }
                }
                #pragma unroll
                for (int mf = 0; mf < 2; ++mf)
                    #pragma unroll
                    for (int i = 0; i < 4; ++i)
                        acc[mf][h * 4 + i] = __builtin_amdgcn_mfma_f32_16x16x32_bf16(
                            af[mf], bf[i], acc[mf][h * 4 + i], 0, 0, 0);
            }
        }

        // epilogue: bias + relu + row-mask -> per-lane column partials
        #pragma unroll
        for (int nf = 0; nf < 8; ++nf) {
            float bb = bv[nf];
            #pragma unroll
            for (int mf = 0; mf < 2; ++mf) {
                int rbase = rbk * BM + wid * 32 + mf * 16 + l4 * 4;
                #pragma unroll
                for (int r = 0; r < 4; ++r) {
                    float v = fmaxf(acc[mf][nf][r] + bb, 0.f);
                    if (rbase + r < N) csum[nf] += v;
                }
            }
        }
    }

    // cross-lane column reduce: lanes l, l^16, l^32, l^48 share a column
    #pragma unroll
    for (int nf = 0; nf < 8; ++nf) {
        float s = csum[nf];
        s += __shfl_xor(s, 16);
        s += __shfl_xor(s, 32);
        if (lane < 16) ldsPart[wid][nf * 16 + lane] = s;
    }
    __syncthreads();
    if (tid < 128) {
        float s = ldsPart[0][tid] + ldsPart[1][tid] + ldsPart[2][tid] + ldsPart[3][tid];
        partial[(size_t)slot * 512 + cb * 128 + tid] = s;
    }
}

__global__ void reduce_partials(const float* __restrict__ partial,
                                float* __restrict__ out, int slots)
{
    int c = threadIdx.x;
    if (c < 512) {
        float s = 0.f;
        for (int i = 0; i < slots; ++i) s += partial[(size_t)i * 512 + c];
        out[c] = s;
    }
}

extern "C" void kernel_launch(void* const* d_in, const int* in_sizes, int n_in,
                              void* d_out, int out_size, void* d_ws, size_t ws_size,
                              hipStream_t stream)
{
    const float* v0 = (const float*)d_in[0];
    const float* v1 = (const float*)d_in[1];
    const float* Wf = (const float*)d_in[2];
    const float* b  = (const float*)d_in[3];
    float* out      = (float*)d_out;

    int N = in_sizes[0] / 256;
    int numRB = (N + BM - 1) / BM;

    const size_t wbytes = (size_t)512 * 512 * sizeof(unsigned short);   // 512 KB
    auto pbytes = [](int s) { return (size_t)s * 512 * sizeof(float); };

    int slots; bool useWb;
    if      (ws_size >= wbytes + pbytes(256)) { slots = 256; useWb = true;  }
    else if (ws_size >= wbytes + pbytes(128)) { slots = 128; useWb = true;  }
    else if (ws_size >= pbytes(256))          { slots = 256; useWb = false; }
    else                                      { slots = 128; useWb = false; }

    if (useWb) {
        unsigned short* Wb = (unsigned short*)d_ws;
        float* partial = (float*)((char*)d_ws + wbytes);
        conv_w_bf16<<<dim3(256), dim3(256), 0, stream>>>(Wf, Wb);
        fused_gemm_pool<true><<<dim3(slots * NCB), dim3(256), 0, stream>>>(
            v0, v1, Wb, Wf, b, partial, N, numRB, slots);
        reduce_partials<<<dim3(1), dim3(512), 0, stream>>>(partial, out, slots);
    } else {
        float* partial = (float*)d_ws;
        fused_gemm_pool<false><<<dim3(slots * NCB), dim3(256), 0, stream>>>(
            v0, v1, nullptr, Wf, b, partial, N, numRB, slots);
        reduce_partials<<<dim3(1), dim3(512), 0, stream>>>(partial, out, slots);
    }
}